// Round 2
// baseline (3170.857 us; speedup 1.0000x reference)
//
#include <hip/hip_runtime.h>
#include <hip/hip_bf16.h>
#include <math.h>

#define N_B   64
#define DIM   256
#define SEQ   1024
#define CF    0.32768f        // (1-2*eta)^5
#define CF2   0.1073741824f   // CF^2
#define BETA  0.59049f        // (1-eta)^5
#define EPSC  1e-10f
#define NSWEEP 10

// ws layout in floats:
// [0]=decay [1]=trDD, [16..271]=bmean, then D(64*256), DDT(64*64), M(1024*256)
#define OFF_BMEAN 16
#define OFF_D     (OFF_BMEAN + DIM)
#define OFF_DDT   (OFF_D + N_B*DIM)
#define OFF_M     (OFF_DDT + N_B*N_B)

__global__ __launch_bounds__(256) void prep_kernel(const float* __restrict__ bubbles,
                                                   const float* __restrict__ mdecay,
                                                   float* __restrict__ ws) {
    int d = threadIdx.x;
    float s = 0.f;
    for (int b = 0; b < N_B; ++b) s += bubbles[b*DIM + d];
    float bm = s * (1.f/64.f);
    ws[OFF_BMEAN + d] = bm;
    float sq = 0.f;
    for (int b = 0; b < N_B; ++b) {
        float v = bubbles[b*DIM + d] - bm;
        ws[OFF_D + b*DIM + d] = v;
        sq += v*v;
    }
    __shared__ float red[256];
    red[d] = sq;
    __syncthreads();
    for (int o = 128; o > 0; o >>= 1) {
        if (d < o) red[d] += red[d+o];
        __syncthreads();
    }
    if (d == 0) {
        ws[1] = red[0];                               // ||D||_F^2 = tr(D D^T)
        ws[0] = 1.f/(1.f + expf(-mdecay[0]));         // sigmoid(memory_decay)
    }
}

__global__ __launch_bounds__(64) void ddt_kernel(float* __restrict__ ws) {
    const float* Dm = ws + OFF_D;
    int i = blockIdx.x, j = threadIdx.x;
    __shared__ float row[DIM];
    #pragma unroll
    for (int u = 0; u < 4; ++u) row[j + 64*u] = Dm[i*DIM + j + 64*u];
    __syncthreads();
    float acc = 0.f;
    #pragma unroll 8
    for (int k = 0; k < DIM; ++k) acc += row[k] * Dm[j*DIM + k];
    ws[OFF_DDT + i*64 + j] = acc;
}

__global__ __launch_bounds__(256) void scan_kernel(const int* __restrict__ tokens,
                                                   const float* __restrict__ embed,
                                                   float* __restrict__ ws) {
    int d = threadIdx.x;
    float decay = ws[0];
    float bm = ws[OFF_BMEAN + d];
    const float omd = 1.f - decay;
    const float omb = 1.f - BETA;
    float mu = 0.f;
    for (int t0 = 0; t0 < SEQ; t0 += 16) {
        float x[16];
        #pragma unroll
        for (int u = 0; u < 16; ++u)
            x[u] = embed[tokens[t0+u]*DIM + d];        // batched independent gathers
        #pragma unroll
        for (int u = 0; u < 16; ++u) {
            float xwm = x[u] + decay*mu;
            float m = BETA*bm + omb*xwm;
            ws[OFF_M + (t0+u)*DIM + d] = m;
            mu = decay*mu + omd*m;
        }
    }
}

__device__ inline void jpair(int r, int k, int& p, int& q) {
    if (k == 0) { p = 63; q = r; }
    else {
        int a = r + k; if (a >= 63) a -= 63;
        int b = r - k; if (b < 0)  b += 63;
        p = a; q = b;
    }
}

__global__ __launch_bounds__(64) void step_kernel(const float* __restrict__ ws,
                                                  float* __restrict__ out) {
    const int t = blockIdx.x;
    const int lane = threadIdx.x;
    __shared__ float A[64][65];   // +1 pad -> 2-way bank aliasing (free)
    __shared__ float yv[64];
    __shared__ float ml[DIM];
    __shared__ float csc[32], css[32];

    const float* Dm  = ws + OFF_D;
    const float* DDT = ws + OFF_DDT;
    const float* m   = ws + OFF_M + t*DIM;

    #pragma unroll
    for (int u = 0; u < 4; ++u) ml[lane + 64*u] = m[lane + 64*u];
    __syncthreads();

    // |m|^2
    float pp = 0.f;
    #pragma unroll
    for (int u = 0; u < 4; ++u) { float v = ml[lane + 64*u]; pp += v*v; }
    #pragma unroll
    for (int o = 1; o < 64; o <<= 1) pp += __shfl_xor(pp, o);
    const float mm2 = pp;

    // y = D m  (coalesced loads + butterfly reduce)
    for (int i = 0; i < 64; ++i) {
        float part = 0.f;
        #pragma unroll
        for (int u = 0; u < 4; ++u)
            part += Dm[i*DIM + 64*u + lane] * ml[64*u + lane];
        #pragma unroll
        for (int o = 1; o < 64; o <<= 1) part += __shfl_xor(part, o);
        if (lane == 0) yv[i] = part;
    }
    __syncthreads();

    const float trDD = ws[1];
    const float tr  = mm2 + (CF2/64.f)*trDD;          // trace(rho)
    const float inv = 1.f/(64.f*tr);
    const float ylane = yv[lane];
    for (int i = 0; i < 64; ++i)
        A[i][lane] = (mm2 + CF*(yv[i] + ylane) + CF2*DDT[i*64 + lane]) * inv;
    __syncthreads();

    // cyclic parallel Jacobi, round-robin ordering
    for (int sw = 0; sw < NSWEEP; ++sw) {
        for (int r = 0; r < 63; ++r) {
            if (lane < 32) {
                int p, q; jpair(r, lane, p, q);
                float app = A[p][p], aqq = A[q][q], apq = A[p][q];
                float cc = 1.f, ss = 0.f;
                if (fabsf(apq) > 1e-36f) {
                    float tau = (aqq - app)/(2.f*apq);
                    float tt = 1.f/(fabsf(tau) + sqrtf(1.f + tau*tau));
                    if (tau < 0.f) tt = -tt;
                    cc = rsqrtf(1.f + tt*tt);
                    ss = tt*cc;
                }
                csc[lane] = cc; css[lane] = ss;
            }
            __syncthreads();
            // column update: A <- A J  (lane owns row 'lane')
            #pragma unroll 4
            for (int k = 0; k < 32; ++k) {
                int p, q; jpair(r, k, p, q);
                float cc = csc[k], ss = css[k];
                float x = A[lane][p], z = A[lane][q];
                A[lane][p] = cc*x - ss*z;
                A[lane][q] = ss*x + cc*z;
            }
            __syncthreads();
            // row update: A <- J^T A  (lane owns column 'lane')
            #pragma unroll 4
            for (int k = 0; k < 32; ++k) {
                int p, q; jpair(r, k, p, q);
                float cc = csc[k], ss = css[k];
                float x = A[p][lane], z = A[q][lane];
                A[p][lane] = cc*x - ss*z;
                A[q][lane] = ss*x + cc*z;
            }
            __syncthreads();
        }
    }

    // eigenvalues = diagonal; bitonic sort ascending across 64 lanes
    float v = A[lane][lane];
    #pragma unroll
    for (int k = 2; k <= 64; k <<= 1) {
        #pragma unroll
        for (int j = k >> 1; j > 0; j >>= 1) {
            float other = __shfl_xor(v, j);
            bool up = ((lane & k) == 0);
            bool lower = ((lane & j) == 0);
            v = (lower == up) ? fminf(v, other) : fmaxf(v, other);
        }
    }

    const float S = 1.f + 192.f*EPSC;   // sum of clipped distribution
    const float invS = 1.f/S;
    float* o = out + t*DIM;
    o[lane]        = EPSC*invS;
    o[64 + lane]   = EPSC*invS;
    o[128 + lane]  = EPSC*invS;
    o[192 + lane]  = fmaxf(v, EPSC)*invS;
}

extern "C" void kernel_launch(void* const* d_in, const int* in_sizes, int n_in,
                              void* d_out, int out_size, void* d_ws, size_t ws_size,
                              hipStream_t stream) {
    const int*   tokens  = (const int*)d_in[0];
    const float* embed   = (const float*)d_in[1];
    const float* bubbles = (const float*)d_in[2];
    const float* mdecay  = (const float*)d_in[3];
    float* out = (float*)d_out;
    float* ws  = (float*)d_ws;

    hipLaunchKernelGGL(prep_kernel, dim3(1),    dim3(256), 0, stream, bubbles, mdecay, ws);
    hipLaunchKernelGGL(ddt_kernel,  dim3(64),   dim3(64),  0, stream, ws);
    hipLaunchKernelGGL(scan_kernel, dim3(1),    dim3(256), 0, stream, tokens, embed, ws);
    hipLaunchKernelGGL(step_kernel, dim3(1024), dim3(64),  0, stream, ws, out);
}

// Round 3
// 809.718 us; speedup vs baseline: 3.9160x; 3.9160x over previous
//
#include <hip/hip_runtime.h>
#include <hip/hip_bf16.h>
#include <math.h>

#define N_B   64
#define DIM   256
#define SEQ   1024
#define CF    0.32768f        // (1-2*eta)^5
#define CF2   0.1073741824f   // CF^2
#define BETA  0.59049f        // (1-eta)^5
#define EPSC  1e-10f
#define NSWEEP 8

// ws layout in floats:
// [0]=decay [1]=trDD, [16..271]=bmean, Dt(256*64), DDT(64*64), M(1024*256)
#define OFF_BMEAN 16
#define OFF_DT    (OFF_BMEAN + DIM)          // Dt[k][b] = bubbles[b][k]-bmean[k]
#define OFF_DDT   (OFF_DT + DIM*N_B)
#define OFF_M     (OFF_DDT + N_B*N_B)

__global__ __launch_bounds__(256) void prep_kernel(const float* __restrict__ bubbles,
                                                   const float* __restrict__ mdecay,
                                                   float* __restrict__ ws) {
    int d = threadIdx.x;
    float s = 0.f;
    for (int b = 0; b < N_B; ++b) s += bubbles[b*DIM + d];
    float bm = s * (1.f/64.f);
    ws[OFF_BMEAN + d] = bm;
    float sq = 0.f;
    for (int b = 0; b < N_B; ++b) {
        float v = bubbles[b*DIM + d] - bm;
        ws[OFF_DT + d*N_B + b] = v;          // transposed store
        sq += v*v;
    }
    __shared__ float red[256];
    red[d] = sq;
    __syncthreads();
    for (int o = 128; o > 0; o >>= 1) {
        if (d < o) red[d] += red[d+o];
        __syncthreads();
    }
    if (d == 0) {
        ws[1] = red[0];                               // ||D||_F^2 = tr(D D^T)
        ws[0] = 1.f/(1.f + expf(-mdecay[0]));         // sigmoid(memory_decay)
    }
}

// DDT[i][j] = sum_k Dt[k][i]*Dt[k][j]
__global__ __launch_bounds__(64) void ddt_kernel(float* __restrict__ ws) {
    const float* Dt = ws + OFF_DT;
    int i = blockIdx.x, j = threadIdx.x;
    __shared__ float coli[DIM];
    #pragma unroll
    for (int kk = 0; kk < 4; ++kk) coli[j + 64*kk] = Dt[(j + 64*kk)*N_B + i];
    __syncthreads();
    float acc = 0.f;
    #pragma unroll 8
    for (int k = 0; k < DIM; ++k) acc += coli[k] * Dt[k*N_B + j];
    ws[OFF_DDT + i*64 + j] = acc;
}

__global__ __launch_bounds__(256) void scan_kernel(const int* __restrict__ tokens,
                                                   const float* __restrict__ embed,
                                                   float* __restrict__ ws) {
    int d = threadIdx.x;
    float decay = ws[0];
    float bm = ws[OFF_BMEAN + d];
    const float omd = 1.f - decay;
    const float omb = 1.f - BETA;
    float mu = 0.f;
    for (int t0 = 0; t0 < SEQ; t0 += 16) {
        float x[16];
        #pragma unroll
        for (int u = 0; u < 16; ++u)
            x[u] = embed[tokens[t0+u]*DIM + d];        // batched independent gathers
        #pragma unroll
        for (int u = 0; u < 16; ++u) {
            float xwm = x[u] + decay*mu;
            float m = BETA*bm + omb*xwm;
            ws[OFF_M + (t0+u)*DIM + d] = m;
            mu = decay*mu + omd*m;
        }
    }
}

__device__ __forceinline__ void jpair(int r, int k, int& p, int& q) {
    if (k == 0) { p = 63; q = r; }
    else {
        int a = r + k; if (a >= 63) a -= 63;
        int b = r - k; if (b < 0)  b += 63;
        p = a; q = b;
    }
}

__global__ __launch_bounds__(256) void step_kernel(const float* __restrict__ ws,
                                                   float* __restrict__ out) {
    const int t    = blockIdx.x;
    const int tid  = threadIdx.x;
    const int lane = tid & 63;
    const int w    = tid >> 6;

    __shared__ float A[64][65];     // +1 pad: bank(i*65+j) = (i+j)%32, conflict-free col access
    __shared__ float yv[64];
    __shared__ float ml[DIM];
    __shared__ float csc[32], css[32];
    __shared__ float ypart[4][64];
    __shared__ float wpart[4];
    __shared__ float sorted[64];

    const float* Dt  = ws + OFF_DT;
    const float* DDT = ws + OFF_DDT;
    const float* m   = ws + OFF_M + (size_t)t*DIM;

    // load m, compute |m|^2 (block reduce)
    float mv = m[tid];
    ml[tid] = mv;
    float pp = mv*mv;
    #pragma unroll
    for (int o = 1; o < 64; o <<= 1) pp += __shfl_xor(pp, o);
    if (lane == 0) wpart[w] = pp;
    __syncthreads();
    const float mm2 = wpart[0]+wpart[1]+wpart[2]+wpart[3];

    // y = D m : wave w handles k-chunk [64w, 64w+64), coalesced Dt reads
    {
        float acc = 0.f;
        const float* DtB = Dt + (w*64)*N_B + lane;
        #pragma unroll 8
        for (int kk = 0; kk < 64; ++kk) acc += DtB[kk*N_B] * ml[w*64 + kk];
        ypart[w][lane] = acc;
    }
    __syncthreads();
    if (tid < 64) yv[tid] = ypart[0][tid]+ypart[1][tid]+ypart[2][tid]+ypart[3][tid];
    __syncthreads();

    const float trDD = ws[1];
    const float tr   = mm2 + (CF2/64.f)*trDD;          // trace(rho)
    const float inv  = 1.f/(64.f*tr);

    // build A: thread -> row i = tid/4, 16 cols starting at (tid%4)*16
    {
        int i  = tid >> 2;
        int jb = (tid & 3) * 16;
        const float4* dd = (const float4*)(DDT + i*64 + jb);
        float yi = yv[i];
        #pragma unroll
        for (int u = 0; u < 4; ++u) {
            float4 d4 = dd[u];
            int j = jb + u*4;
            A[i][j+0] = (mm2 + CF*(yi + yv[j+0]) + CF2*d4.x) * inv;
            A[i][j+1] = (mm2 + CF*(yi + yv[j+1]) + CF2*d4.y) * inv;
            A[i][j+2] = (mm2 + CF*(yi + yv[j+2]) + CF2*d4.z) * inv;
            A[i][j+3] = (mm2 + CF*(yi + yv[j+3]) + CF2*d4.w) * inv;
        }
    }
    __syncthreads();

    // cyclic parallel Jacobi; fused two-sided update: each thread owns 4 2x2 blocks
    const int a  = tid >> 3;       // pair index for rows, 0..31
    const int bg = tid & 7;        // 4 col-pair group, 0..7
    for (int sw = 0; sw < NSWEEP; ++sw) {
        for (int r = 0; r < 63; ++r) {
            if (tid < 32) {
                int p, q; jpair(r, tid, p, q);
                float app = A[p][p], aqq = A[q][q], apq = A[p][q];
                float cc = 1.f, ss = 0.f;
                if (fabsf(apq) > 1e-36f) {
                    float tau = (aqq - app)/(2.f*apq);
                    float tt  = 1.f/(fabsf(tau) + sqrtf(1.f + tau*tau));
                    if (tau < 0.f) tt = -tt;
                    cc = rsqrtf(1.f + tt*tt);
                    ss = tt*cc;
                }
                csc[tid] = cc; css[tid] = ss;
            }
            __syncthreads();

            int pa, qa; jpair(r, a, pa, qa);
            const float ca = csc[a], sa = css[a];
            int pb[4], qb[4];
            float x00[4], x01[4], x10[4], x11[4];
            #pragma unroll
            for (int u = 0; u < 4; ++u) {
                jpair(r, bg*4 + u, pb[u], qb[u]);
                x00[u] = A[pa][pb[u]]; x01[u] = A[pa][qb[u]];
                x10[u] = A[qa][pb[u]]; x11[u] = A[qa][qb[u]];
            }
            #pragma unroll
            for (int u = 0; u < 4; ++u) {
                const float cb = csc[bg*4+u], sb = css[bg*4+u];
                float y00 = cb*x00[u] - sb*x01[u];
                float y01 = sb*x00[u] + cb*x01[u];
                float y10 = cb*x10[u] - sb*x11[u];
                float y11 = sb*x10[u] + cb*x11[u];
                A[pa][pb[u]] = ca*y00 - sa*y10;
                A[pa][qb[u]] = ca*y01 - sa*y11;
                A[qa][pb[u]] = sa*y00 + ca*y10;
                A[qa][qb[u]] = sa*y01 + ca*y11;
            }
            __syncthreads();
        }
    }

    // eigenvalues = diagonal; bitonic sort ascending across wave 0
    if (tid < 64) {
        float v = A[tid][tid];
        #pragma unroll
        for (int k = 2; k <= 64; k <<= 1) {
            #pragma unroll
            for (int j = k >> 1; j > 0; j >>= 1) {
                float other = __shfl_xor(v, j);
                bool up    = ((tid & k) == 0);
                bool lower = ((tid & j) == 0);
                v = (lower == up) ? fminf(v, other) : fmaxf(v, other);
            }
        }
        sorted[tid] = v;
    }
    __syncthreads();

    const float invS = 1.f/(1.f + 192.f*EPSC);
    out[(size_t)t*DIM + tid] = (tid < 192) ? EPSC*invS
                                           : fmaxf(sorted[tid-192], EPSC)*invS;
}

extern "C" void kernel_launch(void* const* d_in, const int* in_sizes, int n_in,
                              void* d_out, int out_size, void* d_ws, size_t ws_size,
                              hipStream_t stream) {
    const int*   tokens  = (const int*)d_in[0];
    const float* embed   = (const float*)d_in[1];
    const float* bubbles = (const float*)d_in[2];
    const float* mdecay  = (const float*)d_in[3];
    float* out = (float*)d_out;
    float* ws  = (float*)d_ws;

    hipLaunchKernelGGL(prep_kernel, dim3(1),    dim3(256), 0, stream, bubbles, mdecay, ws);
    hipLaunchKernelGGL(ddt_kernel,  dim3(64),   dim3(64),  0, stream, ws);
    hipLaunchKernelGGL(scan_kernel, dim3(1),    dim3(256), 0, stream, tokens, embed, ws);
    hipLaunchKernelGGL(step_kernel, dim3(1024), dim3(256), 0, stream, ws, out);
}

// Round 5
// 648.439 us; speedup vs baseline: 4.8900x; 1.2487x over previous
//
#include <hip/hip_runtime.h>
#include <hip/hip_bf16.h>
#include <math.h>

#define N_B   64
#define DIM   256
#define SEQ   1024
#define CF    0.32768f        // (1-2*eta)^5
#define CF2   0.1073741824f   // CF^2
#define BETA  0.59049f        // (1-eta)^5
#define EPSC  1e-10f
#define NSWEEP 6

// ws layout in floats:
// [0]=decay [1]=trDD, [16..271]=bmean, Dt(256*64), DDT(64*64), M(1024*256)
#define OFF_BMEAN 16
#define OFF_DT    (OFF_BMEAN + DIM)          // Dt[k][b] = bubbles[b][k]-bmean[k]
#define OFF_DDT   (OFF_DT + DIM*N_B)
#define OFF_M     (OFF_DDT + N_B*N_B)

__global__ __launch_bounds__(256) void prep_kernel(const float* __restrict__ bubbles,
                                                   const float* __restrict__ mdecay,
                                                   float* __restrict__ ws) {
    int d = threadIdx.x;
    float s = 0.f;
    for (int b = 0; b < N_B; ++b) s += bubbles[b*DIM + d];
    float bm = s * (1.f/64.f);
    ws[OFF_BMEAN + d] = bm;
    float sq = 0.f;
    for (int b = 0; b < N_B; ++b) {
        float v = bubbles[b*DIM + d] - bm;
        ws[OFF_DT + d*N_B + b] = v;          // transposed store
        sq += v*v;
    }
    __shared__ float red[256];
    red[d] = sq;
    __syncthreads();
    for (int o = 128; o > 0; o >>= 1) {
        if (d < o) red[d] += red[d+o];
        __syncthreads();
    }
    if (d == 0) {
        ws[1] = red[0];                               // ||D||_F^2 = tr(D D^T)
        ws[0] = 1.f/(1.f + expf(-mdecay[0]));         // sigmoid(memory_decay)
    }
}

// DDT[i][j] = sum_k Dt[k][i]*Dt[k][j]
__global__ __launch_bounds__(64) void ddt_kernel(float* __restrict__ ws) {
    const float* Dt = ws + OFF_DT;
    int i = blockIdx.x, j = threadIdx.x;
    __shared__ float coli[DIM];
    #pragma unroll
    for (int kk = 0; kk < 4; ++kk) coli[j + 64*kk] = Dt[(j + 64*kk)*N_B + i];
    __syncthreads();
    float acc = 0.f;
    #pragma unroll 8
    for (int k = 0; k < DIM; ++k) acc += coli[k] * Dt[k*N_B + j];
    ws[OFF_DDT + i*64 + j] = acc;
}

__global__ __launch_bounds__(256) void scan_kernel(const int* __restrict__ tokens,
                                                   const float* __restrict__ embed,
                                                   float* __restrict__ ws) {
    int d = threadIdx.x;
    float decay = ws[0];
    float bm = ws[OFF_BMEAN + d];
    const float omd = 1.f - decay;
    const float omb = 1.f - BETA;
    float mu = 0.f;
    for (int t0 = 0; t0 < SEQ; t0 += 16) {
        float x[16];
        #pragma unroll
        for (int u = 0; u < 16; ++u)
            x[u] = embed[tokens[t0+u]*DIM + d];        // batched independent gathers
        #pragma unroll
        for (int u = 0; u < 16; ++u) {
            float xwm = x[u] + decay*mu;
            float m = BETA*bm + omb*xwm;
            ws[OFF_M + (t0+u)*DIM + d] = m;
            mu = decay*mu + omd*m;
        }
    }
}

__global__ __launch_bounds__(256) void step_kernel(const float* __restrict__ ws,
                                                   float* __restrict__ out) {
    const int t    = blockIdx.x;
    const int tid  = threadIdx.x;
    const int lane = tid & 63;
    const int w    = tid >> 6;

    __shared__ float A[64][65];     // bank(i,j) = (i+j)%32
    __shared__ float yv[64];
    __shared__ float ml[DIM];
    __shared__ float csc[32], css[32];
    __shared__ float ypart[4][64];
    __shared__ float wpart[4];
    __shared__ float sorted[64];

    const float* Dt  = ws + OFF_DT;
    const float* DDT = ws + OFF_DDT;
    const float* m   = ws + OFF_M + (size_t)t*DIM;

    // load m, compute |m|^2 (block reduce)
    float mv = m[tid];
    ml[tid] = mv;
    float pp = mv*mv;
    #pragma unroll
    for (int o = 1; o < 64; o <<= 1) pp += __shfl_xor(pp, o);
    if (lane == 0) wpart[w] = pp;
    __syncthreads();
    const float mm2 = wpart[0]+wpart[1]+wpart[2]+wpart[3];

    // y = D m : wave w handles k-chunk [64w, 64w+64), coalesced Dt reads
    {
        float acc = 0.f;
        const float* DtB = Dt + (w*64)*N_B + lane;
        #pragma unroll 8
        for (int kk = 0; kk < 64; ++kk) acc += DtB[kk*N_B] * ml[w*64 + kk];
        ypart[w][lane] = acc;
    }
    __syncthreads();
    if (tid < 64) yv[tid] = ypart[0][tid]+ypart[1][tid]+ypart[2][tid]+ypart[3][tid];
    __syncthreads();

    const float trDD = ws[1];
    const float tr   = mm2 + (CF2/64.f)*trDD;          // trace(rho)
    const float inv  = 1.f/(64.f*tr);

    // build A: thread -> row i = tid/4, 16 cols starting at (tid%4)*16
    {
        int i  = tid >> 2;
        int jb = (tid & 3) * 16;
        const float4* dd = (const float4*)(DDT + i*64 + jb);
        float yi = yv[i];
        #pragma unroll
        for (int u = 0; u < 4; ++u) {
            float4 d4 = dd[u];
            int j = jb + u*4;
            A[i][j+0] = (mm2 + CF*(yi + yv[j+0]) + CF2*d4.x) * inv;
            A[i][j+1] = (mm2 + CF*(yi + yv[j+1]) + CF2*d4.y) * inv;
            A[i][j+2] = (mm2 + CF*(yi + yv[j+2]) + CF2*d4.z) * inv;
            A[i][j+3] = (mm2 + CF*(yi + yv[j+3]) + CF2*d4.w) * inv;
        }
    }
    __syncthreads();

    // cyclic parallel Jacobi, fused two-sided 2x2 update.
    // Lane remap for bank-conflict-free LDS: row-pair a = tid&31 (32 consecutive
    // rows per half-wave -> 32 distinct banks in [64][65] layout), col-group
    // bg = tid>>5. Tournament indices maintained incrementally (+1 mod 63,
    // period 63 = one sweep, so they roll over sweeps with no reset).
    const int a  = tid & 31;
    const int bg = tid >> 5;

    int pa, qa;
    if (a == 0) { pa = 63; qa = 0; }
    else        { pa = a;  qa = 63 - a; }
    int pb[4], qb[4];
    #pragma unroll
    for (int u = 0; u < 4; ++u) {
        int k = bg*4 + u;
        if (k == 0) { pb[u] = 63; qb[u] = 0; }
        else        { pb[u] = k;  qb[u] = 63 - k; }
    }

    for (int rr = 0; rr < NSWEEP*63; ++rr) {
        if (tid < 32) {
            // slot tid: its own (pa,qa) are this slot's tournament pair
            float app = A[pa][pa], aqq = A[qa][qa], apq = A[pa][qa];
            float cc = 1.f, ss = 0.f;
            if (fabsf(apq) > 1e-36f) {
                float tau = (aqq - app)/(2.f*apq);
                float tt  = 1.f/(fabsf(tau) + sqrtf(1.f + tau*tau));
                if (tau < 0.f) tt = -tt;
                cc = rsqrtf(1.f + tt*tt);
                ss = tt*cc;
            }
            csc[tid] = cc; css[tid] = ss;
        }
        __syncthreads();

        const float ca = csc[a], sa = css[a];
        float2 x0[4], x1[4];
        #pragma unroll
        for (int u = 0; u < 4; ++u) {
            x0[u] = make_float2(A[pa][pb[u]], A[pa][qb[u]]);
            x1[u] = make_float2(A[qa][pb[u]], A[qa][qb[u]]);
        }
        #pragma unroll
        for (int u = 0; u < 4; ++u) {
            const float cb = csc[bg*4+u], sb = css[bg*4+u];
            // column rotation within each row's float2
            float2 t0 = make_float2(cb*x0[u].x - sb*x0[u].y, sb*x0[u].x + cb*x0[u].y);
            float2 t1 = make_float2(cb*x1[u].x - sb*x1[u].y, sb*x1[u].x + cb*x1[u].y);
            // row rotation: elementwise across the two float2s (pk-fma friendly)
            float2 r0 = make_float2(ca*t0.x - sa*t1.x, ca*t0.y - sa*t1.y);
            float2 r1 = make_float2(sa*t0.x + ca*t1.x, sa*t0.y + ca*t1.y);
            A[pa][pb[u]] = r0.x; A[pa][qb[u]] = r0.y;
            A[qa][pb[u]] = r1.x; A[qa][qb[u]] = r1.y;
        }

        // advance tournament: p(r+1) = p(r)+1 mod 63 (slot-0 top fixed at 63)
        if (a != 0) pa = (pa == 62) ? 0 : pa + 1;
        qa = (qa == 62) ? 0 : qa + 1;
        #pragma unroll
        for (int u = 0; u < 4; ++u) {
            if (u == 0) { if (bg != 0) pb[u] = (pb[u] == 62) ? 0 : pb[u] + 1; }
            else        { pb[u] = (pb[u] == 62) ? 0 : pb[u] + 1; }
            qb[u] = (qb[u] == 62) ? 0 : qb[u] + 1;
        }
        __syncthreads();
    }

    // eigenvalues = diagonal; bitonic sort ascending across wave 0
    if (tid < 64) {
        float v = A[tid][tid];
        #pragma unroll
        for (int k = 2; k <= 64; k <<= 1) {
            #pragma unroll
            for (int j = k >> 1; j > 0; j >>= 1) {
                float other = __shfl_xor(v, j);
                bool up    = ((tid & k) == 0);
                bool lower = ((tid & j) == 0);
                v = (lower == up) ? fminf(v, other) : fmaxf(v, other);
            }
        }
        sorted[tid] = v;
    }
    __syncthreads();

    const float invS = 1.f/(1.f + 192.f*EPSC);
    out[(size_t)t*DIM + tid] = (tid < 192) ? EPSC*invS
                                           : fmaxf(sorted[tid-192], EPSC)*invS;
}

extern "C" void kernel_launch(void* const* d_in, const int* in_sizes, int n_in,
                              void* d_out, int out_size, void* d_ws, size_t ws_size,
                              hipStream_t stream) {
    const int*   tokens  = (const int*)d_in[0];
    const float* embed   = (const float*)d_in[1];
    const float* bubbles = (const float*)d_in[2];
    const float* mdecay  = (const float*)d_in[3];
    float* out = (float*)d_out;
    float* ws  = (float*)d_ws;

    hipLaunchKernelGGL(prep_kernel, dim3(1),    dim3(256), 0, stream, bubbles, mdecay, ws);
    hipLaunchKernelGGL(ddt_kernel,  dim3(64),   dim3(64),  0, stream, ws);
    hipLaunchKernelGGL(scan_kernel, dim3(1),    dim3(256), 0, stream, tokens, embed, ws);
    hipLaunchKernelGGL(step_kernel, dim3(1024), dim3(256), 0, stream, ws, out);
}

// Round 6
// 469.334 us; speedup vs baseline: 6.7561x; 1.3816x over previous
//
#include <hip/hip_runtime.h>
#include <hip/hip_bf16.h>
#include <math.h>

#define N_B   64
#define DIM   256
#define SEQ   1024
#define CF    0.32768f        // (1-2*eta)^5
#define CF2   0.1073741824f   // CF^2
#define BETA  0.59049f        // (1-eta)^5
#define EPSC  1e-10f
#define NSWEEP 4

// ws layout in floats:
// [0]=decay [1]=trDD, [16..271]=bmean, Dt(256*64), DDT(64*64), M(1024*256)
#define OFF_BMEAN 16
#define OFF_DT    (OFF_BMEAN + DIM)          // Dt[k][b] = bubbles[b][k]-bmean[k]
#define OFF_DDT   (OFF_DT + DIM*N_B)
#define OFF_M     (OFF_DDT + N_B*N_B)

__global__ __launch_bounds__(256) void prep_kernel(const float* __restrict__ bubbles,
                                                   const float* __restrict__ mdecay,
                                                   float* __restrict__ ws) {
    int d = threadIdx.x;
    float s = 0.f;
    for (int b = 0; b < N_B; ++b) s += bubbles[b*DIM + d];
    float bm = s * (1.f/64.f);
    ws[OFF_BMEAN + d] = bm;
    float sq = 0.f;
    for (int b = 0; b < N_B; ++b) {
        float v = bubbles[b*DIM + d] - bm;
        ws[OFF_DT + d*N_B + b] = v;          // transposed store
        sq += v*v;
    }
    __shared__ float red[256];
    red[d] = sq;
    __syncthreads();
    for (int o = 128; o > 0; o >>= 1) {
        if (d < o) red[d] += red[d+o];
        __syncthreads();
    }
    if (d == 0) {
        ws[1] = red[0];                               // ||D||_F^2 = tr(D D^T)
        ws[0] = 1.f/(1.f + expf(-mdecay[0]));         // sigmoid(memory_decay)
    }
}

// DDT[i][j] = sum_k Dt[k][i]*Dt[k][j]
__global__ __launch_bounds__(64) void ddt_kernel(float* __restrict__ ws) {
    const float* Dt = ws + OFF_DT;
    int i = blockIdx.x, j = threadIdx.x;
    __shared__ float coli[DIM];
    #pragma unroll
    for (int kk = 0; kk < 4; ++kk) coli[j + 64*kk] = Dt[(j + 64*kk)*N_B + i];
    __syncthreads();
    float acc = 0.f;
    #pragma unroll 8
    for (int k = 0; k < DIM; ++k) acc += coli[k] * Dt[k*N_B + j];
    ws[OFF_DDT + i*64 + j] = acc;
}

__global__ __launch_bounds__(256) void scan_kernel(const int* __restrict__ tokens,
                                                   const float* __restrict__ embed,
                                                   float* __restrict__ ws) {
    int d = threadIdx.x;
    float decay = ws[0];
    float bm = ws[OFF_BMEAN + d];
    const float omd = 1.f - decay;
    const float omb = 1.f - BETA;
    float mu = 0.f;
    for (int t0 = 0; t0 < SEQ; t0 += 16) {
        float x[16];
        #pragma unroll
        for (int u = 0; u < 16; ++u)
            x[u] = embed[tokens[t0+u]*DIM + d];        // batched independent gathers
        #pragma unroll
        for (int u = 0; u < 16; ++u) {
            float xwm = x[u] + decay*mu;
            float m = BETA*bm + omb*xwm;
            ws[OFF_M + (t0+u)*DIM + d] = m;
            mu = decay*mu + omd*m;
        }
    }
}

__global__ __launch_bounds__(256) void step_kernel(const float* __restrict__ ws,
                                                   float* __restrict__ out) {
    const int t    = blockIdx.x;
    const int tid  = threadIdx.x;
    const int lane = tid & 63;
    const int w    = tid >> 6;

    __shared__ float A[64][65];     // bank(i,j) = (i+j)%32
    __shared__ float yv[64];
    __shared__ float ml[DIM];
    __shared__ float2 cs[32];       // (c,s) packed: 5x b64 reads/thread/round
    __shared__ float ypart[4][64];
    __shared__ float wpart[4];
    __shared__ float sorted[64];

    const float* Dt  = ws + OFF_DT;
    const float* DDT = ws + OFF_DDT;
    const float* m   = ws + OFF_M + (size_t)t*DIM;

    // load m, compute |m|^2 (block reduce)
    float mv = m[tid];
    ml[tid] = mv;
    float pp = mv*mv;
    #pragma unroll
    for (int o = 1; o < 64; o <<= 1) pp += __shfl_xor(pp, o);
    if (lane == 0) wpart[w] = pp;
    __syncthreads();
    const float mm2 = wpart[0]+wpart[1]+wpart[2]+wpart[3];

    // y = D m : wave w handles k-chunk [64w, 64w+64), coalesced Dt reads
    {
        float acc = 0.f;
        const float* DtB = Dt + (w*64)*N_B + lane;
        #pragma unroll 8
        for (int kk = 0; kk < 64; ++kk) acc += DtB[kk*N_B] * ml[w*64 + kk];
        ypart[w][lane] = acc;
    }
    __syncthreads();
    if (tid < 64) yv[tid] = ypart[0][tid]+ypart[1][tid]+ypart[2][tid]+ypart[3][tid];
    __syncthreads();

    const float trDD = ws[1];
    const float tr   = mm2 + (CF2/64.f)*trDD;          // trace(rho)
    const float inv  = 1.f/(64.f*tr);

    // build A: thread -> row i = tid/4, 16 cols starting at (tid%4)*16
    {
        int i  = tid >> 2;
        int jb = (tid & 3) * 16;
        const float4* dd = (const float4*)(DDT + i*64 + jb);
        float yi = yv[i];
        #pragma unroll
        for (int u = 0; u < 4; ++u) {
            float4 d4 = dd[u];
            int j = jb + u*4;
            A[i][j+0] = (mm2 + CF*(yi + yv[j+0]) + CF2*d4.x) * inv;
            A[i][j+1] = (mm2 + CF*(yi + yv[j+1]) + CF2*d4.y) * inv;
            A[i][j+2] = (mm2 + CF*(yi + yv[j+2]) + CF2*d4.z) * inv;
            A[i][j+3] = (mm2 + CF*(yi + yv[j+3]) + CF2*d4.w) * inv;
        }
    }
    __syncthreads();

    // cyclic parallel Jacobi, fused two-sided 2x2 update.
    // Lane remap for bank-conflict-free LDS: row-pair a = tid&31, col-group
    // bg = tid>>5. Tournament indices maintained incrementally (+1 mod 63,
    // period 63 = one sweep, so they roll over sweeps with no reset).
    const int a  = tid & 31;
    const int bg = tid >> 5;

    int pa, qa;
    if (a == 0) { pa = 63; qa = 0; }
    else        { pa = a;  qa = 63 - a; }
    int pb[4], qb[4];
    #pragma unroll
    for (int u = 0; u < 4; ++u) {
        int k = bg*4 + u;
        if (k == 0) { pb[u] = 63; qb[u] = 0; }
        else        { pb[u] = k;  qb[u] = 63 - k; }
    }

    for (int rr = 0; rr < NSWEEP*63; ++rr) {
        if (tid < 32) {
            // slot tid: its own (pa,qa) are this slot's tournament pair
            float app = A[pa][pa], aqq = A[qa][qa], apq = A[pa][qa];
            float cc = 1.f, ss = 0.f;
            if (fabsf(apq) > 1e-36f) {
                float tau = (aqq - app)/(2.f*apq);
                float tt  = 1.f/(fabsf(tau) + sqrtf(1.f + tau*tau));
                if (tau < 0.f) tt = -tt;
                cc = rsqrtf(1.f + tt*tt);
                ss = tt*cc;
            }
            cs[tid] = make_float2(cc, ss);
        }
        __syncthreads();

        const float2 csa = cs[a];
        const float ca = csa.x, sa = csa.y;
        float2 csb[4];
        #pragma unroll
        for (int u = 0; u < 4; ++u) csb[u] = cs[bg*4+u];

        float2 x0[4], x1[4];
        #pragma unroll
        for (int u = 0; u < 4; ++u) {
            x0[u] = make_float2(A[pa][pb[u]], A[pa][qb[u]]);
            x1[u] = make_float2(A[qa][pb[u]], A[qa][qb[u]]);
        }
        #pragma unroll
        for (int u = 0; u < 4; ++u) {
            const float cb = csb[u].x, sb = csb[u].y;
            // column rotation within each row's float2
            float2 t0 = make_float2(cb*x0[u].x - sb*x0[u].y, sb*x0[u].x + cb*x0[u].y);
            float2 t1 = make_float2(cb*x1[u].x - sb*x1[u].y, sb*x1[u].x + cb*x1[u].y);
            // row rotation: elementwise across the two float2s
            float2 r0 = make_float2(ca*t0.x - sa*t1.x, ca*t0.y - sa*t1.y);
            float2 r1 = make_float2(sa*t0.x + ca*t1.x, sa*t0.y + ca*t1.y);
            A[pa][pb[u]] = r0.x; A[pa][qb[u]] = r0.y;
            A[qa][pb[u]] = r1.x; A[qa][qb[u]] = r1.y;
        }

        // advance tournament: p(r+1) = p(r)+1 mod 63 (slot-0 top fixed at 63)
        if (a != 0) pa = (pa == 62) ? 0 : pa + 1;
        qa = (qa == 62) ? 0 : qa + 1;
        #pragma unroll
        for (int u = 0; u < 4; ++u) {
            if (u == 0) { if (bg != 0) pb[u] = (pb[u] == 62) ? 0 : pb[u] + 1; }
            else        { pb[u] = (pb[u] == 62) ? 0 : pb[u] + 1; }
            qb[u] = (qb[u] == 62) ? 0 : qb[u] + 1;
        }
        __syncthreads();
    }

    // eigenvalues = diagonal; bitonic sort ascending across wave 0
    if (tid < 64) {
        float v = A[tid][tid];
        #pragma unroll
        for (int k = 2; k <= 64; k <<= 1) {
            #pragma unroll
            for (int j = k >> 1; j > 0; j >>= 1) {
                float other = __shfl_xor(v, j);
                bool up    = ((tid & k) == 0);
                bool lower = ((tid & j) == 0);
                v = (lower == up) ? fminf(v, other) : fmaxf(v, other);
            }
        }
        sorted[tid] = v;
    }
    __syncthreads();

    const float invS = 1.f/(1.f + 192.f*EPSC);
    out[(size_t)t*DIM + tid] = (tid < 192) ? EPSC*invS
                                           : fmaxf(sorted[tid-192], EPSC)*invS;
}

extern "C" void kernel_launch(void* const* d_in, const int* in_sizes, int n_in,
                              void* d_out, int out_size, void* d_ws, size_t ws_size,
                              hipStream_t stream) {
    const int*   tokens  = (const int*)d_in[0];
    const float* embed   = (const float*)d_in[1];
    const float* bubbles = (const float*)d_in[2];
    const float* mdecay  = (const float*)d_in[3];
    float* out = (float*)d_out;
    float* ws  = (float*)d_ws;

    hipLaunchKernelGGL(prep_kernel, dim3(1),    dim3(256), 0, stream, bubbles, mdecay, ws);
    hipLaunchKernelGGL(ddt_kernel,  dim3(64),   dim3(64),  0, stream, ws);
    hipLaunchKernelGGL(scan_kernel, dim3(1),    dim3(256), 0, stream, tokens, embed, ws);
    hipLaunchKernelGGL(step_kernel, dim3(1024), dim3(256), 0, stream, ws, out);
}

// Round 7
// 362.963 us; speedup vs baseline: 8.7360x; 1.2931x over previous
//
#include <hip/hip_runtime.h>
#include <hip/hip_bf16.h>
#include <math.h>

#define N_B   64
#define DIM   256
#define SEQ   1024
#define CF    0.32768f        // (1-2*eta)^5
#define CF2   0.1073741824f   // CF^2
#define BETA  0.59049f        // (1-eta)^5
#define EPSC  1e-10f
#define NSWEEP 3
#define ROUNDS (NSWEEP*63)

// ws layout in floats:
// [0]=decay [1]=trDD, [16..271]=bmean, Dt(256*64), DDT(64*64), M(1024*256)
#define OFF_BMEAN 16
#define OFF_DT    (OFF_BMEAN + DIM)          // Dt[k][b] = bubbles[b][k]-bmean[k]
#define OFF_DDT   (OFF_DT + DIM*N_B)
#define OFF_M     (OFF_DDT + N_B*N_B)

__global__ __launch_bounds__(256) void prep_kernel(const float* __restrict__ bubbles,
                                                   const float* __restrict__ mdecay,
                                                   float* __restrict__ ws) {
    int d = threadIdx.x;
    float s = 0.f;
    for (int b = 0; b < N_B; ++b) s += bubbles[b*DIM + d];
    float bm = s * (1.f/64.f);
    ws[OFF_BMEAN + d] = bm;
    float sq = 0.f;
    for (int b = 0; b < N_B; ++b) {
        float v = bubbles[b*DIM + d] - bm;
        ws[OFF_DT + d*N_B + b] = v;          // transposed store
        sq += v*v;
    }
    __shared__ float red[256];
    red[d] = sq;
    __syncthreads();
    for (int o = 128; o > 0; o >>= 1) {
        if (d < o) red[d] += red[d+o];
        __syncthreads();
    }
    if (d == 0) {
        ws[1] = red[0];                               // ||D||_F^2 = tr(D D^T)
        ws[0] = 1.f/(1.f + expf(-mdecay[0]));         // sigmoid(memory_decay)
    }
}

// DDT[i][j] = sum_k Dt[k][i]*Dt[k][j]
__global__ __launch_bounds__(64) void ddt_kernel(float* __restrict__ ws) {
    const float* Dt = ws + OFF_DT;
    int i = blockIdx.x, j = threadIdx.x;
    __shared__ float coli[DIM];
    #pragma unroll
    for (int kk = 0; kk < 4; ++kk) coli[j + 64*kk] = Dt[(j + 64*kk)*N_B + i];
    __syncthreads();
    float acc = 0.f;
    #pragma unroll 8
    for (int k = 0; k < DIM; ++k) acc += coli[k] * Dt[k*N_B + j];
    ws[OFF_DDT + i*64 + j] = acc;
}

__global__ __launch_bounds__(256) void scan_kernel(const int* __restrict__ tokens,
                                                   const float* __restrict__ embed,
                                                   float* __restrict__ ws) {
    int d = threadIdx.x;
    float decay = ws[0];
    float bm = ws[OFF_BMEAN + d];
    const float omd = 1.f - decay;
    const float omb = 1.f - BETA;
    float mu = 0.f;
    for (int t0 = 0; t0 < SEQ; t0 += 16) {
        float x[16];
        #pragma unroll
        for (int u = 0; u < 16; ++u)
            x[u] = embed[tokens[t0+u]*DIM + d];        // batched independent gathers
        #pragma unroll
        for (int u = 0; u < 16; ++u) {
            float xwm = x[u] + decay*mu;
            float m = BETA*bm + omb*xwm;
            ws[OFF_M + (t0+u)*DIM + d] = m;
            mu = decay*mu + omd*m;
        }
    }
}

// upper-triangle storage address for symmetric A in a [64][65] buffer
__device__ __forceinline__ int triaddr(int i, int j) {
    int mn = min(i, j), mx = max(i, j);
    return mn*65 + mx;
}

// linear id L in [0,496) -> slot-pair (a<b), a,b in [0,32)
__device__ __forceinline__ void tri_decomp(int L, int& a, int& b) {
    int a_ = 0, S = 0;
    while (S + (31 - a_) <= L) { S += 31 - a_; ++a_; }
    a = a_; b = a_ + 1 + (L - S);
}

#define SLOT_INIT(k, p, q, f) { f = ((k) == 0); p = f ? 63 : (k); q = f ? 0 : (63 - (k)); }
#define SLOT_ADV(p, q, f)     { if (!(f)) p = (p == 62) ? 0 : p + 1; q = (q == 62) ? 0 : q + 1; }

__global__ __launch_bounds__(256) void step_kernel(const float* __restrict__ ws,
                                                   float* __restrict__ out) {
    const int t    = blockIdx.x;
    const int tid  = threadIdx.x;
    const int lane = tid & 63;
    const int w    = tid >> 6;

    __shared__ float A[64][65];     // symmetric: only i<=j locations authoritative
    __shared__ float yv[64];
    __shared__ float ml[DIM];
    __shared__ float2 cs[32];
    __shared__ float ypart[4][64];
    __shared__ float wpart[4];
    __shared__ float sorted[64];

    float* Ad = &A[0][0];
    const float* Dt  = ws + OFF_DT;
    const float* DDT = ws + OFF_DDT;
    const float* m   = ws + OFF_M + (size_t)t*DIM;

    // load m, compute |m|^2 (block reduce)
    float mv = m[tid];
    ml[tid] = mv;
    float pp = mv*mv;
    #pragma unroll
    for (int o = 1; o < 64; o <<= 1) pp += __shfl_xor(pp, o);
    if (lane == 0) wpart[w] = pp;
    __syncthreads();
    const float mm2 = wpart[0]+wpart[1]+wpart[2]+wpart[3];

    // y = D m : wave w handles k-chunk [64w, 64w+64), coalesced Dt reads
    {
        float acc = 0.f;
        const float* DtB = Dt + (w*64)*N_B + lane;
        #pragma unroll 8
        for (int kk = 0; kk < 64; ++kk) acc += DtB[kk*N_B] * ml[w*64 + kk];
        ypart[w][lane] = acc;
    }
    __syncthreads();
    if (tid < 64) yv[tid] = ypart[0][tid]+ypart[1][tid]+ypart[2][tid]+ypart[3][tid];
    __syncthreads();

    const float trDD = ws[1];
    const float tr   = mm2 + (CF2/64.f)*trDD;          // trace(rho)
    const float inv  = 1.f/(64.f*tr);

    // build A (full square; lower triangle written but never read)
    {
        int i  = tid >> 2;
        int jb = (tid & 3) * 16;
        const float4* dd = (const float4*)(DDT + i*64 + jb);
        float yi = yv[i];
        #pragma unroll
        for (int u = 0; u < 4; ++u) {
            float4 d4 = dd[u];
            int j = jb + u*4;
            A[i][j+0] = (mm2 + CF*(yi + yv[j+0]) + CF2*d4.x) * inv;
            A[i][j+1] = (mm2 + CF*(yi + yv[j+1]) + CF2*d4.y) * inv;
            A[i][j+2] = (mm2 + CF*(yi + yv[j+2]) + CF2*d4.z) * inv;
            A[i][j+3] = (mm2 + CF*(yi + yv[j+3]) + CF2*d4.w) * inv;
        }
    }
    __syncthreads();

    // ---- symmetric cyclic Jacobi on the upper triangle ----
    // 32 tournament slots; slot k at round r pairs ((k+r)%63 | 63, (r-k)%63).
    // 496 off-diagonal slot-blocks -> 248 threads x 2 blocks; diagonal 2x2
    // blocks handled by the 32 angle threads via the t-identities.
    const bool active = (tid < 248);

    int kr0 = 0, kc0 = 1, kr1 = 0, kc1 = 1;
    if (active) { tri_decomp(2*tid, kr0, kc0); tri_decomp(2*tid+1, kr1, kc1); }

    int pr0, qr0, pc0, qc0, pr1, qr1, pc1, qc1;
    bool fr0, fc0, fr1, fc1;
    SLOT_INIT(kr0, pr0, qr0, fr0);
    SLOT_INIT(kc0, pc0, qc0, fc0);
    SLOT_INIT(kr1, pr1, qr1, fr1);
    SLOT_INIT(kc1, pc1, qc1, fc1);

    int pA = 63, qA = 0; bool fA;
    if (tid < 32) SLOT_INIT(tid, pA, qA, fA);

    for (int rr = 0; rr < ROUNDS; ++rr) {
        if (tid < 32) {
            // angle + diagonal-block update for slot tid
            int aqp = triaddr(pA, qA);
            float app = Ad[pA*65 + pA];
            float aqq = Ad[qA*65 + qA];
            float apq = Ad[aqp];
            float ccf = 1.f, ssf = 0.f, ttf = 0.f;
            if (fabsf(apq) > 1e-36f) {
                float tau = (aqq - app)/(2.f*apq);
                ttf = 1.f/(fabsf(tau) + sqrtf(1.f + tau*tau));
                if (tau < 0.f) ttf = -ttf;
                ccf = rsqrtf(1.f + ttf*ttf);
                ssf = ttf*ccf;
            }
            cs[tid] = make_float2(ccf, ssf);
            Ad[pA*65 + pA] = app - ttf*apq;
            Ad[qA*65 + qA] = aqq + ttf*apq;
            Ad[aqp] = 0.f;
        }
        __syncthreads();

        if (active) {
            // block 0
            {
                float2 cr = cs[kr0], cc2 = cs[kc0];
                int a00 = triaddr(pr0, pc0), a01 = triaddr(pr0, qc0);
                int a10 = triaddr(qr0, pc0), a11 = triaddr(qr0, qc0);
                float x00 = Ad[a00], x01 = Ad[a01], x10 = Ad[a10], x11 = Ad[a11];
                float t0x = cc2.x*x00 - cc2.y*x01, t0y = cc2.y*x00 + cc2.x*x01;
                float t1x = cc2.x*x10 - cc2.y*x11, t1y = cc2.y*x10 + cc2.x*x11;
                Ad[a00] = cr.x*t0x - cr.y*t1x;
                Ad[a01] = cr.x*t0y - cr.y*t1y;
                Ad[a10] = cr.y*t0x + cr.x*t1x;
                Ad[a11] = cr.y*t0y + cr.x*t1y;
            }
            // block 1
            {
                float2 cr = cs[kr1], cc2 = cs[kc1];
                int a00 = triaddr(pr1, pc1), a01 = triaddr(pr1, qc1);
                int a10 = triaddr(qr1, pc1), a11 = triaddr(qr1, qc1);
                float x00 = Ad[a00], x01 = Ad[a01], x10 = Ad[a10], x11 = Ad[a11];
                float t0x = cc2.x*x00 - cc2.y*x01, t0y = cc2.y*x00 + cc2.x*x01;
                float t1x = cc2.x*x10 - cc2.y*x11, t1y = cc2.y*x10 + cc2.x*x11;
                Ad[a00] = cr.x*t0x - cr.y*t1x;
                Ad[a01] = cr.x*t0y - cr.y*t1y;
                Ad[a10] = cr.y*t0x + cr.x*t1x;
                Ad[a11] = cr.y*t0y + cr.x*t1y;
            }
        }

        SLOT_ADV(pr0, qr0, fr0);
        SLOT_ADV(pc0, qc0, fc0);
        SLOT_ADV(pr1, qr1, fr1);
        SLOT_ADV(pc1, qc1, fc1);
        if (tid < 32) SLOT_ADV(pA, qA, fA);
        __syncthreads();
    }

    // eigenvalues = diagonal; bitonic sort ascending across wave 0
    if (tid < 64) {
        float v = A[tid][tid];
        #pragma unroll
        for (int k = 2; k <= 64; k <<= 1) {
            #pragma unroll
            for (int j = k >> 1; j > 0; j >>= 1) {
                float other = __shfl_xor(v, j);
                bool up    = ((tid & k) == 0);
                bool lower = ((tid & j) == 0);
                v = (lower == up) ? fminf(v, other) : fmaxf(v, other);
            }
        }
        sorted[tid] = v;
    }
    __syncthreads();

    const float invS = 1.f/(1.f + 192.f*EPSC);
    out[(size_t)t*DIM + tid] = (tid < 192) ? EPSC*invS
                                           : fmaxf(sorted[tid-192], EPSC)*invS;
}

extern "C" void kernel_launch(void* const* d_in, const int* in_sizes, int n_in,
                              void* d_out, int out_size, void* d_ws, size_t ws_size,
                              hipStream_t stream) {
    const int*   tokens  = (const int*)d_in[0];
    const float* embed   = (const float*)d_in[1];
    const float* bubbles = (const float*)d_in[2];
    const float* mdecay  = (const float*)d_in[3];
    float* out = (float*)d_out;
    float* ws  = (float*)d_ws;

    hipLaunchKernelGGL(prep_kernel, dim3(1),    dim3(256), 0, stream, bubbles, mdecay, ws);
    hipLaunchKernelGGL(ddt_kernel,  dim3(64),   dim3(64),  0, stream, ws);
    hipLaunchKernelGGL(scan_kernel, dim3(1),    dim3(256), 0, stream, tokens, embed, ws);
    hipLaunchKernelGGL(step_kernel, dim3(1024), dim3(256), 0, stream, ws, out);
}